// Round 1
// baseline (75.078 us; speedup 1.0000x reference)
//
#include <hip/hip_runtime.h>

// Problem constants (from the reference)
#define B_    8
#define C_    8
#define L_    4096
#define F_    32
#define K_    10
#define PROC_ 20
#define STEP_ 5
#define NW_   815   // len(range(0, L-PROC-STEP+1, STEP)); CHAN_OUT == NW_ (no pad region)

// One DTW: kernel taps kk[] (scalar, block-uniform) vs 20-float window at win.
// 3 VALU ops/cell: v_sub, v_min3, v_fma — minimal for the in-register
// recurrence (min3 + accumulate-add are irreducibly scalar per cell; packed
// f32 (r2) and packed f16 (r4) variants both measured SLOWER).
__device__ __forceinline__ float dtw_one(const float* __restrict__ win,
                                         const float kk[K_])
{
    float wv[PROC_];
    #pragma unroll
    for (int j = 0; j < PROC_; ++j) wv[j] = win[j];

    float row[PROC_];
    {
        float d = kk[0] - wv[0];
        row[0] = d * d;
        #pragma unroll
        for (int j = 1; j < PROC_; ++j) {
            float dj = kk[0] - wv[j];
            row[j] = fmaf(dj, dj, row[j - 1]);
        }
    }
    #pragma unroll
    for (int i = 1; i < K_; ++i) {
        float diag = row[0];
        float d0 = kk[i] - wv[0];
        float cur = fmaf(d0, d0, diag);
        row[0] = cur;
        float left = cur;
        #pragma unroll
        for (int j = 1; j < PROC_; ++j) {
            float up = row[j];
            float dj = kk[i] - wv[j];
            float m = fminf(fminf(left, up), diag);  // v_min3_f32
            cur = fmaf(dj, dj, m);
            diag = up;
            row[j] = cur;
            left = cur;
        }
    }
    return row[PROC_ - 1];
}

// 8 waves/SIMD (64-VGPR cap): state wv[20]+row[20]=40 VGPR, kk -> SGPRs.
// 2048 blocks = 8 blocks/CU exactly; issue-saturated at this occupancy.
__global__ __launch_bounds__(256, 8) void dtw_kernel(
    const float* __restrict__ x,      // (B, C, L)
    const float* __restrict__ kern,   // (F, K)
    float* __restrict__ out)          // (B, C*F, NW)
{
    __shared__ float sx[L_];

    const int blk = blockIdx.x;          // 0 .. B*C*F-1
    const int f = blk & (F_ - 1);        // fastest
    const int c = (blk >> 5) & (C_ - 1);
    const int b = blk >> 8;

    // Stage x[b][c][:] into LDS with float4 loads (4096 floats = 1024 float4)
    const float4* x4 = reinterpret_cast<const float4*>(x + ((size_t)(b * C_ + c)) * L_);
    float4* s4 = reinterpret_cast<float4*>(sx);
    #pragma unroll
    for (int i = 0; i < L_ / 4 / 256; ++i)
        s4[threadIdx.x + i * 256] = x4[threadIdx.x + i * 256];

    // Kernel taps: block-uniform loads -> SGPRs
    float kk[K_];
    #pragma unroll
    for (int i = 0; i < K_; ++i) kk[i] = kern[f * K_ + i];

    __syncthreads();

    float* outp = out + ((size_t)b * (C_ * F_) + (c * F_ + f)) * (size_t)NW_;
    const int tid = threadIdx.x;

    // 3 uniform rounds: w = tid, tid+256, tid+512 (max 767 < 815) — no masking.
    #pragma unroll
    for (int r = 0; r < 3; ++r) {
        const int w = tid + r * 256;
        outp[w] = dtw_one(sx + w * STEP_, kk);
    }

    // Masked tail round: windows 768..814 (47 DTWs) on exactly ONE wave of the
    // block (others skip via execz — masked lanes don't save issue, so keeping
    // it in one wave minimizes total wave-rounds: {4,3,3,3} = 13/block).
    //
    // KEY CHANGE vs r6: rotate WHICH wave owns the tail. Wave i maps to SIMD
    // i%4, so pinning the tail to wave 0 piled all 8 co-resident blocks' 4th
    // round onto SIMD0 (32 wave-rounds vs 24 on SIMDs 1-3 — a ~23% makespan
    // penalty). Rotation key must vary across CO-RESIDENT blocks, which differ
    // in the HIGH bits of blockIdx (n, n+256, ...), so fold bit 8+ in:
    // (blk + (blk>>8)) & 3 covers all 4 wave slots under both consecutive and
    // strided block->CU assignment. Balanced: 26 wave-rounds per SIMD.
    {
        const int tail_wave = (blk + (blk >> 8)) & 3;
        if ((tid >> 6) == tail_wave) {
            const int w = 768 + (tid & 63);
            if (w < NW_) outp[w] = dtw_one(sx + w * STEP_, kk);
        }
    }
}

extern "C" void kernel_launch(void* const* d_in, const int* in_sizes, int n_in,
                              void* d_out, int out_size, void* d_ws, size_t ws_size,
                              hipStream_t stream) {
    const float* x    = (const float*)d_in[0];   // (8, 8, 4096) fp32
    const float* kern = (const float*)d_in[1];   // (32, 10) fp32
    float* out        = (float*)d_out;           // (8, 256, 815) fp32

    dim3 grid(B_ * C_ * F_);   // 2048 blocks
    dim3 block(256);
    hipLaunchKernelGGL(dtw_kernel, grid, block, 0, stream, x, kern, out);
}